// Round 7
// baseline (1478.695 us; speedup 1.0000x reference)
//
#include <hip/hip_runtime.h>
#include <hip/hip_bf16.h>
#include <stdint.h>

#define N_ATOMS 40000
#define N_BONDS 90000
#define MAX_NB 6
#define ATOM_FDIM 133
#define BOND_FDIM 147
#define HIDDEN 300
#define DEPTH 6

// padded dims
#define KB_PAD 160      // bond fdim 147 -> 160
#define KA_PAD 160      // atom fdim 133 -> 160
#define HP 320          // hidden 300 -> 320
#define NB_PAD 90112    // bonds padded to mult of 128 (704 tiles)
#define NA_PAD 40064    // atoms padded to mult of 128 (313 tiles)

typedef unsigned short u16;
typedef unsigned int uint32;

typedef __bf16 bf16x8 __attribute__((ext_vector_type(8)));
typedef float f32x4 __attribute__((ext_vector_type(4)));

#define GLOBAL_AS __attribute__((address_space(1)))
#define LDS_AS __attribute__((address_space(3)))

__device__ __forceinline__ void async_copy16(const void* g, void* l) {
    __builtin_amdgcn_global_load_lds((GLOBAL_AS void*)(void*)g,
                                     (LDS_AS void*)l, 16, 0, 0);
}

__device__ __forceinline__ float bf2f(u16 s) {
    union { uint32 u; float f; } v; v.u = ((uint32)s) << 16; return v.f;
}
__device__ __forceinline__ u16 f2bf(float f) {
    union { float f; uint32 u; } v; v.f = f;
    uint32 r = v.u + 0x7fffu + ((v.u >> 16) & 1u);
    return (u16)(r >> 16);
}
// single-instruction RTNE pack of two f32 -> two bf16 (gfx950)
__device__ __forceinline__ uint32 cvt_pk_bf16(float lo, float hi) {
    uint32 r;
    asm("v_cvt_pk_bf16_f32 %0, %1, %2" : "=v"(r) : "v"(lo), "v"(hi));
    return r;
}
__device__ __forceinline__ u16 f2bf1(float f) {
    return (u16)(cvt_pk_bf16(f, f) & 0xffffu);
}
__device__ __forceinline__ float sigm(float x) { return 1.f / (1.f + __expf(-x)); }
__device__ __forceinline__ float tanh_s(float x) {
    float e = __expf(-2.f * fabsf(x));
    float t = (1.f - e) / (1.f + e);
    return x >= 0.f ? t : -t;
}

#define WAITV(n) asm volatile("s_waitcnt vmcnt(" #n ")" ::: "memory")
#define MEMFENCE asm volatile("" ::: "memory")

// ---------------------------------------------------------------------------
// GEMM: per gate g: C_g[M x 320] = A[M x K] @ B_g[320 x K]^T, bf16 in, fp32 acc.
// Block tile: 128 rows x 64 cols x NG B-slots, 4 waves as 2M x 2N.
//
// A is NOT staged in LDS. The 16x16x32 A-fragment layout (lane(l16,lhalf) <-
// A[row=l16][k=lhalf*8..+8]) is exactly a row-major global read at 16 B/lane,
// so A-fragments load global->VGPR directly (4 x global_load_dwordx4 per wave
// per kstep). Register double buffer aR[2][4], DISTANCE-1 prefetch:
// at iter j we load A(j+1) into set (j+1)&1 while compute(j) reads set j&1.
// (R5 bug: distance-2 into 2 sets aliased the live set -> wrong results.)
// The compiler auto-inserts exact vmcnt waits for aR uses; manual WAITV only
// has to guarantee B(j) is in LDS before the barrier.
//
// Issue order per iter j (pinned by MEMFENCE):
//   WAITV(newer-than-B(j))   steady: B(j+1)+A(j) = NG+4 (7 for NG=3, 5 for 1);
//                            last iter: A(j) = 4
//   s_barrier                -> all waves' B(j) resident
//   stageB(j+2)              -> buf (j+2)%3 (readers drained: compute(j-1)'s
//                            lgkm waits retired its ds_reads before barrier)
//   loadA(j+1) -> aR[(j+1)&1]
//   compute(j)               (T5 setprio around MFMA cluster)
// B LDS: 3 rotating buffers x NG*4 KB, T2 both-sides swizzle (conflicts = 0).
// launch_bounds (256,2): EPI3 acc alone is 128 regs -> 2 blocks/CU is the cap;
// min_waves=4 would force a 128-reg cap and spill (R5's second bug).
//
// EPI 3 gate sparsity: 3 staged B-slots; slot2 = i_n (ks<KSPLIT) / h_n (else).
// EPI 0: store bf16. EPI 2: bias+relu+mask fp32 out. EPI 3: fused GRU.
// ---------------------------------------------------------------------------
template<int NG, int EPI, int SWZ, int KSTEPS, int KSPLIT>
__global__ __launch_bounds__(256, 2) void gemm_k(
    const u16* __restrict__ A, int ldaB,
    const u16* __restrict__ A2, int lda2B,
    const u16* __restrict__ Bw, int ldbB,
    int M,
    u16* __restrict__ C1, int ldc,
    const float* __restrict__ bias,
    const u16* __restrict__ hbuf,
    float* __restrict__ outp, const float* __restrict__ omask)
{
    constexpr int NACC = (EPI == 3) ? 4 : NG;
    __shared__ __align__(16) u16 lsB[3][NG * 64 * 32];

    const int tid = threadIdx.x;
    const int wv = tid >> 6, ln = tid & 63;
    const int wm = wv >> 1, wn = wv & 1;        // 2M x 2N wave grid
    int bxi, byi;
    if constexpr (SWZ) {
        int bid = blockIdx.x;
        int chunk = bid & 7, pos = bid >> 3;
        int orig = chunk * (int)(gridDim.x >> 3) + pos;
        bxi = orig / 5; byi = orig - bxi * 5;
    } else {
        bxi = blockIdx.x; byi = blockIdx.y;
    }
    const int m0 = bxi * 128;
    const int n0 = byi * 64;
    const int lhalf = ln >> 4, l16 = ln & 15;

    f32x4 acc[NACC][4][2];
#pragma unroll
    for (int g = 0; g < NACC; ++g)
#pragma unroll
        for (int r = 0; r < 4; ++r)
#pragma unroll
            for (int c = 0; c < 2; ++c) { f32x4 z = {0.f, 0.f, 0.f, 0.f}; acc[g][r][c] = z; }

    // ---- A fragment-direct base pointers (lane(l16,lhalf) = row l16, k lhalf*8) ----
    const char* pAf[4];
    const char* pA2f[4];
#pragma unroll
    for (int r = 0; r < 4; ++r) {
        int row = m0 + wm * 64 + r * 16 + l16;
        pAf[r]  = (const char*)A  + (size_t)row * ldaB  + lhalf * 16;
        pA2f[r] = (const char*)A2 + (size_t)row * lda2B + lhalf * 16;
    }
    // ---- B staging base (source pre-swizzled; glds dest lane-linear) ----
    const int bidx = wv * 64 + ln;
    const int bn = bidx >> 2;
    const int bkb = ((bidx & 3) * 16) ^ (((bn >> 1) & 3) << 4);
    const char* pB[NG];
#pragma unroll
    for (int g = 0; g < NG; ++g)
        pB[g] = (const char*)Bw + (size_t)(g * 320 + n0 + bn) * ldbB + bkb;
    const char* pB2hi = (const char*)Bw + (size_t)(3 * 320 + n0 + bn) * ldbB + bkb;

    bf16x8 aR[2][4];

    auto stageB = [&](int ks) {
        const int buf = ks % 3;
#pragma unroll
        for (int g = 0; g < NG; ++g) {
            const char* src;
            if constexpr (EPI == 3) {
                if (g == 2) src = ((ks < KSPLIT) ? pB[2] : pB2hi) + ks * 64;
                else        src = pB[g] + ks * 64;
            } else {
                src = pB[g] + ks * 64;
            }
            async_copy16(src, &lsB[buf][g * 2048 + wv * 512]);
        }
    };

    auto loadA = [&](int ks, int set) {
#pragma unroll
        for (int r = 0; r < 4; ++r) {
            const char* src = (ks < KSPLIT) ? (pAf[r] + ks * 64)
                                            : (pA2f[r] + (ks - KSPLIT) * 64);
            aR[set][r] = *(const bf16x8*)src;
        }
    };

    const int rswz = ((l16 >> 1) & 3) << 3;      // B read-side swizzle (u16 units)

    auto compute = [&](int j) {
        const int buf = j % 3;
        const int set = j & 1;
        __builtin_amdgcn_s_setprio(1);
#pragma unroll
        for (int g = 0; g < NG; ++g) {
#pragma unroll
            for (int c = 0; c < 2; ++c) {
                bf16x8 bf = *(const bf16x8*)&lsB[buf][g * 2048 + (wn * 32 + c * 16 + l16) * 32 + (lhalf * 8 ^ rswz)];
#pragma unroll
                for (int r = 0; r < 4; ++r) {
                    if constexpr (EPI == 3) {
                        if (g == 2) {
                            if (j < KSPLIT)
                                acc[2][r][c] = __builtin_amdgcn_mfma_f32_16x16x32_bf16(aR[set][r], bf, acc[2][r][c], 0, 0, 0);
                            else
                                acc[3][r][c] = __builtin_amdgcn_mfma_f32_16x16x32_bf16(aR[set][r], bf, acc[3][r][c], 0, 0, 0);
                        } else {
                            acc[g][r][c] = __builtin_amdgcn_mfma_f32_16x16x32_bf16(aR[set][r], bf, acc[g][r][c], 0, 0, 0);
                        }
                    } else {
                        acc[g][r][c] = __builtin_amdgcn_mfma_f32_16x16x32_bf16(aR[set][r], bf, acc[g][r][c], 0, 0, 0);
                    }
                }
            }
        }
        __builtin_amdgcn_s_setprio(0);
    };

    // prologue, issue order B(0), B(1), A(0)  (fences pin vmcnt order)
    stageB(0);
    MEMFENCE;
    stageB(1);
    MEMFENCE;
    loadA(0, 0);

#pragma unroll
    for (int j = 0; j < KSTEPS; ++j) {
        if (j < KSTEPS - 1) {
            // newer than B(j): B(j+1) [NG] + A(j) [4]
            if constexpr (NG == 3) WAITV(7); else WAITV(5);
        } else {
            WAITV(4);                             // newer than B(j): A(j) only
        }
        __builtin_amdgcn_s_barrier();             // all waves' B(j) resident
        MEMFENCE;                                 // pin ds_reads below barrier
        if (j + 2 < KSTEPS) {
            stageB(j + 2);                        // buf (j+2)%3: readers drained
            MEMFENCE;                             // keep issue order B then A
        }
        if (j + 1 < KSTEPS) loadA(j + 1, (j + 1) & 1);
        compute(j);
    }

    const int mrow_base = m0 + wm * 64;
#pragma unroll
    for (int r = 0; r < 4; ++r) {
#pragma unroll
        for (int c = 0; c < 2; ++c) {
            int nn_ = n0 + wn * 32 + c * 16 + l16;
#pragma unroll
            for (int i = 0; i < 4; ++i) {
                int m = mrow_base + r * 16 + lhalf * 4 + i;
                if (m >= M) continue;
                if constexpr (EPI == 0) {
#pragma unroll
                    for (int g = 0; g < NG; ++g) {
                        float v = acc[g][r][c][i];
                        if (bias != nullptr && nn_ < HIDDEN) v += bias[g * HIDDEN + nn_];
                        C1[(size_t)m * ldc + g * 320 + nn_] = f2bf1(v);
                    }
                } else if constexpr (EPI == 2) {
                    if (nn_ < HIDDEN) {
                        float v = acc[0][r][c][i] + (bias ? bias[nn_] : 0.f);
                        v = fmaxf(v, 0.f);
                        if (omask) v *= omask[m];
                        outp[(size_t)m * HIDDEN + nn_] = v;
                    }
                } else { // EPI == 3: fused GRU
                    float rl = acc[0][r][c][i] + bias[nn_];
                    float zl = acc[1][r][c][i] + bias[320 + nn_];
                    float in_ = acc[2][r][c][i] + bias[640 + nn_];
                    float hn_ = acc[3][r][c][i] + bias[960 + nn_];
                    float hv = bf2f(hbuf[(size_t)m * HP + nn_]);
                    float rr = sigm(rl);
                    float zz = sigm(zl);
                    float nv = tanh_s(in_ + rr * hn_);
                    float msg = (1.f - zz) * nv + zz * hv;
                    if (m == 0) msg = 0.f;
                    C1[(size_t)m * HP + nn_] = f2bf1(msg);
                }
            }
        }
    }
}

// a_message[a, :] = sum_j message[a2b[a,j], :]   (bf16, 320-col padded rows)
__global__ __launch_bounds__(256) void gather_sum_k(
    const u16* __restrict__ msg, const int* __restrict__ a2b, u16* __restrict__ amsg)
{
    int u = blockIdx.x * 256 + threadIdx.x;
    if (u >= N_ATOMS * 40) return;
    int a = u / 40, c = u - a * 40;
    const uint4* mp = (const uint4*)msg;
    float s[8];
#pragma unroll
    for (int t = 0; t < 8; ++t) s[t] = 0.f;
#pragma unroll
    for (int j = 0; j < MAX_NB; ++j) {
        int b = a2b[a * MAX_NB + j];
        uint4 v = mp[(size_t)b * 40 + c];
        s[0] += bf2f((u16)(v.x & 0xffff)); s[1] += bf2f((u16)(v.x >> 16));
        s[2] += bf2f((u16)(v.y & 0xffff)); s[3] += bf2f((u16)(v.y >> 16));
        s[4] += bf2f((u16)(v.z & 0xffff)); s[5] += bf2f((u16)(v.z >> 16));
        s[6] += bf2f((u16)(v.w & 0xffff)); s[7] += bf2f((u16)(v.w >> 16));
    }
    uint4 o;
    o.x = cvt_pk_bf16(s[0], s[1]);
    o.y = cvt_pk_bf16(s[2], s[3]);
    o.z = cvt_pk_bf16(s[4], s[5]);
    o.w = cvt_pk_bf16(s[6], s[7]);
    ((uint4*)amsg)[(size_t)a * 40 + c] = o;
}

// h[b, :] = amsg[b2a[b], :] - msg[b2revb[b], :]
__global__ __launch_bounds__(256) void build_h_k(
    const u16* __restrict__ amsg, const u16* __restrict__ msg,
    const int* __restrict__ b2a, const int* __restrict__ b2revb, u16* __restrict__ h)
{
    int u = blockIdx.x * 256 + threadIdx.x;
    if (u >= N_BONDS * 40) return;
    int b = u / 40, c = u - b * 40;
    uint4 va = ((const uint4*)amsg)[(size_t)b2a[b] * 40 + c];
    uint4 vm = ((const uint4*)msg)[(size_t)b2revb[b] * 40 + c];
    uint4 o;
    o.x = cvt_pk_bf16(bf2f((u16)(va.x & 0xffff)) - bf2f((u16)(vm.x & 0xffff)),
                      bf2f((u16)(va.x >> 16))    - bf2f((u16)(vm.x >> 16)));
    o.y = cvt_pk_bf16(bf2f((u16)(va.y & 0xffff)) - bf2f((u16)(vm.y & 0xffff)),
                      bf2f((u16)(va.y >> 16))    - bf2f((u16)(vm.y >> 16)));
    o.z = cvt_pk_bf16(bf2f((u16)(va.z & 0xffff)) - bf2f((u16)(vm.z & 0xffff)),
                      bf2f((u16)(va.z >> 16))    - bf2f((u16)(vm.z >> 16)));
    o.w = cvt_pk_bf16(bf2f((u16)(va.w & 0xffff)) - bf2f((u16)(vm.w & 0xffff)),
                      bf2f((u16)(va.w >> 16))    - bf2f((u16)(vm.w >> 16)));
    ((uint4*)h)[(size_t)b * 40 + c] = o;
}

// generic pad+cast fp32 -> bf16
__global__ __launch_bounds__(256) void padcast_k(
    const float* __restrict__ src, int srows, int scols,
    u16* __restrict__ dst, int drows, int dcols)
{
    int idx = blockIdx.x * 256 + threadIdx.x;
    if (idx >= drows * dcols) return;
    int r = idx / dcols, c = idx - r * dcols;
    float v = (r < srows && c < scols) ? src[(size_t)r * scols + c] : 0.f;
    dst[idx] = f2bf(v);
}

// Wf[900][160] fp32 = W_ih[900][300] @ W_i[300][147]  (cols >=147 zero)
__global__ __launch_bounds__(256) void wf_k(
    const float* __restrict__ W_ih, const float* __restrict__ W_i, float* __restrict__ Wf)
{
    int idx = blockIdx.x * 256 + threadIdx.x;
    if (idx >= 900 * 160) return;
    int r = idx / 160, c = idx - r * 160;
    float s = 0.f;
    if (c < BOND_FDIM) {
        for (int k = 0; k < HIDDEN; ++k)
            s += W_ih[(size_t)r * HIDDEN + k] * W_i[(size_t)k * BOND_FDIM + c];
    }
    Wf[idx] = s;
}

// W4[4][320][480] bf16: gate r/z: [Wf_g | W_hh_g]; gate i_n: [Wf_n | 0]; gate h_n: [0 | W_hh_n]
__global__ __launch_bounds__(256) void prep_W4_k(
    const float* __restrict__ Wf, const float* __restrict__ W_hh, u16* __restrict__ W4)
{
    int idx = blockIdx.x * 256 + threadIdx.x;
    if (idx >= 4 * HP * 480) return;
    int g = idx / (HP * 480); int rem = idx - g * HP * 480;
    int n = rem / 480, k = rem - n * 480;
    float v = 0.f;
    if (n < HIDDEN) {
        if (g <= 1) {
            if (k < KB_PAD) v = Wf[(size_t)(g * HIDDEN + n) * 160 + k];
            else if (k < KB_PAD + HIDDEN) v = W_hh[(size_t)(g * HIDDEN + n) * HIDDEN + (k - KB_PAD)];
        } else if (g == 2) {
            if (k < KB_PAD) v = Wf[(size_t)(2 * HIDDEN + n) * 160 + k];
        } else { // g == 3
            if (k >= KB_PAD && k < KB_PAD + HIDDEN) v = W_hh[(size_t)(2 * HIDDEN + n) * HIDDEN + (k - KB_PAD)];
        }
    }
    W4[idx] = f2bf(v);
}

// bias4[4*320] fp32: r: b_ih_r+b_hh_r; z: b_ih_z+b_hh_z; i_n: b_ih_n; h_n: b_hh_n
__global__ __launch_bounds__(256) void bias4_k(
    const float* __restrict__ b_ih, const float* __restrict__ b_hh, float* __restrict__ b4)
{
    int idx = blockIdx.x * 256 + threadIdx.x;
    if (idx >= 4 * HP) return;
    int g = idx / HP, n = idx - g * HP;
    float v = 0.f;
    if (n < HIDDEN) {
        if (g == 0) v = b_ih[n] + b_hh[n];
        else if (g == 1) v = b_ih[HIDDEN + n] + b_hh[HIDDEN + n];
        else if (g == 2) v = b_ih[2 * HIDDEN + n];
        else v = b_hh[2 * HIDDEN + n];
    }
    b4[idx] = v;
}

// W_o [300][433] -> [320][480]: k<133 atom part, k in [160,460) hidden part
__global__ __launch_bounds__(256) void padWo_k(const float* __restrict__ src, u16* __restrict__ dst)
{
    int idx = blockIdx.x * 256 + threadIdx.x;
    if (idx >= HP * 480) return;
    int n = idx / 480, k = idx - n * 480;
    float v = 0.f;
    if (n < HIDDEN) {
        if (k < ATOM_FDIM) v = src[(size_t)n * 433 + k];
        else if (k >= KA_PAD && k < KA_PAD + HIDDEN) v = src[(size_t)n * 433 + ATOM_FDIM + (k - KA_PAD)];
    }
    dst[idx] = f2bf(v);
}

__global__ __launch_bounds__(256) void sentinel_k(float* __restrict__ out, int n)
{
    int i = blockIdx.x * 256 + threadIdx.x;
    if (i < n) out[i] = 31415.0f;
}

extern "C" void kernel_launch(void* const* d_in, const int* in_sizes, int n_in,
                              void* d_out, int out_size, void* d_ws, size_t ws_size,
                              hipStream_t stream)
{
    const float* f_atoms = (const float*)d_in[0];
    const float* f_bonds = (const float*)d_in[1];
    const int*   a2b     = (const int*)d_in[2];
    const int*   b2a     = (const int*)d_in[3];
    const int*   b2revb  = (const int*)d_in[4];
    const float* maskp   = (const float*)d_in[8];
    const float* W_i     = (const float*)d_in[9];
    const float* W_ih    = (const float*)d_in[10];
    const float* W_hh    = (const float*)d_in[11];
    const float* b_ih    = (const float*)d_in[12];
    const float* b_hh    = (const float*)d_in[13];
    const float* W_o_w   = (const float*)d_in[14];
    const float* W_o_b   = (const float*)d_in[15];
    float* out = (float*)d_out;

    char* ws = (char*)d_ws;
    size_t off = 0;
    auto alloc = [&](size_t bytes) -> char* {
        char* p = ws + off;
        off += (bytes + 255) & ~(size_t)255;
        return p;
    };
    u16*   Wi_p   = (u16*)alloc((size_t)HP * KB_PAD * 2);        // [320][160]
    u16*   W4     = (u16*)alloc((size_t)4 * HP * 480 * 2);       // [4][320][480]
    u16*   Wo_p   = (u16*)alloc((size_t)HP * 480 * 2);           // [320][480]
    float* bias4  = (float*)alloc((size_t)4 * HP * 4);           // [4*320]
    float* Wf     = (float*)alloc((size_t)900 * 160 * 4);        // [900][160] fp32
    u16*   fa_p   = (u16*)alloc((size_t)NA_PAD * KA_PAD * 2);    // [40064][160]
    u16*   fb_p   = (u16*)alloc((size_t)NB_PAD * KB_PAD * 2);    // [90112][160]
    u16*   message= (u16*)alloc((size_t)NB_PAD * HP * 2);        // [90112][320]
    u16*   hbuf   = (u16*)alloc((size_t)NB_PAD * HP * 2);
    u16*   amsg   = (u16*)alloc((size_t)NA_PAD * HP * 2);        // [40064][320]

    if (off > ws_size) {  // workspace too small: write sentinel so the failure is identifiable
        sentinel_k<<<(out_size + 255) / 256, 256, 0, stream>>>(out, out_size);
        return;
    }

    // --- weight / feature prep ---
    padcast_k<<<(HP * KB_PAD + 255) / 256, 256, 0, stream>>>(W_i, HIDDEN, BOND_FDIM, Wi_p, HP, KB_PAD);
    padcast_k<<<(NB_PAD * KB_PAD + 255) / 256, 256, 0, stream>>>(f_bonds, N_BONDS, BOND_FDIM, fb_p, NB_PAD, KB_PAD);
    padcast_k<<<(NA_PAD * KA_PAD + 255) / 256, 256, 0, stream>>>(f_atoms, N_ATOMS, ATOM_FDIM, fa_p, NA_PAD, KA_PAD);
    wf_k<<<(900 * 160 + 255) / 256, 256, 0, stream>>>(W_ih, W_i, Wf);
    prep_W4_k<<<(4 * HP * 480 + 255) / 256, 256, 0, stream>>>(Wf, W_hh, W4);
    bias4_k<<<(4 * HP + 255) / 256, 256, 0, stream>>>(b_ih, b_hh, bias4);
    padWo_k<<<(HP * 480 + 255) / 256, 256, 0, stream>>>(W_o_w, Wo_p);

    dim3 blk(256);
    dim3 gB(NB_PAD / 128, 5);
    // message = inp = f_bonds @ W_i.T   (K=160 -> 5 ksteps, A only)
    gemm_k<1, 0, 0, 5, 5><<<gB, blk, 0, stream>>>(
        fb_p, KB_PAD * 2, fb_p, KB_PAD * 2, Wi_p, KB_PAD * 2,
        N_BONDS, message, HP, nullptr, nullptr, nullptr, nullptr);
    dim3 gBf(NB_PAD / 128 * 5);   // flat, 3520 % 8 == 0 -> bijective XCD swizzle
    for (int d = 0; d < DEPTH - 1; ++d) {
        gather_sum_k<<<(N_ATOMS * 40 + 255) / 256, 256, 0, stream>>>(message, a2b, amsg);
        build_h_k<<<(N_BONDS * 40 + 255) / 256, 256, 0, stream>>>(amsg, message, b2a, b2revb, hbuf);
        // fused GRU: A = [f_bonds_pad | h], 3 staged B-slots, 4 acc gates, K = 480
        gemm_k<3, 3, 1, 15, 5><<<gBf, blk, 0, stream>>>(
            fb_p, KB_PAD * 2, hbuf, HP * 2, W4, 480 * 2,
            N_BONDS, message, HP, bias4, hbuf, nullptr, nullptr);
    }
    gather_sum_k<<<(N_ATOMS * 40 + 255) / 256, 256, 0, stream>>>(message, a2b, amsg);
    dim3 gO(NA_PAD / 128, 5);
    gemm_k<1, 2, 0, 15, 5><<<gO, blk, 0, stream>>>(
        fa_p, KA_PAD * 2, amsg, HP * 2, Wo_p, 480 * 2,
        N_ATOMS, nullptr, 0, W_o_b, nullptr, out, maskp);
}

// Round 8
// 1333.790 us; speedup vs baseline: 1.1086x; 1.1086x over previous
//
#include <hip/hip_runtime.h>
#include <hip/hip_bf16.h>
#include <stdint.h>

#define N_ATOMS 40000
#define N_BONDS 90000
#define MAX_NB 6
#define ATOM_FDIM 133
#define BOND_FDIM 147
#define HIDDEN 300
#define DEPTH 6

// padded dims
#define KB_PAD 160
#define KA_PAD 160
#define HP 320
#define NB_PAD 90112    // mult of 128 (704 tiles) and of 64 (1408 tiles)
#define NA_PAD 40064

typedef unsigned short u16;
typedef unsigned int uint32;

typedef __bf16 bf16x8 __attribute__((ext_vector_type(8)));
typedef float f32x4 __attribute__((ext_vector_type(4)));

#define GLOBAL_AS __attribute__((address_space(1)))
#define LDS_AS __attribute__((address_space(3)))

__device__ __forceinline__ void async_copy16(const void* g, void* l) {
    __builtin_amdgcn_global_load_lds((GLOBAL_AS void*)(void*)g,
                                     (LDS_AS void*)l, 16, 0, 0);
}

__device__ __forceinline__ float bf2f(u16 s) {
    union { uint32 u; float f; } v; v.u = ((uint32)s) << 16; return v.f;
}
__device__ __forceinline__ u16 f2bf(float f) {
    union { float f; uint32 u; } v; v.f = f;
    uint32 r = v.u + 0x7fffu + ((v.u >> 16) & 1u);
    return (u16)(r >> 16);
}
__device__ __forceinline__ uint32 cvt_pk_bf16(float lo, float hi) {
    uint32 r;
    asm("v_cvt_pk_bf16_f32 %0, %1, %2" : "=v"(r) : "v"(lo), "v"(hi));
    return r;
}
__device__ __forceinline__ u16 f2bf1(float f) {
    return (u16)(cvt_pk_bf16(f, f) & 0xffffu);
}
__device__ __forceinline__ float sigm(float x) { return 1.f / (1.f + __expf(-x)); }
__device__ __forceinline__ float tanh_s(float x) {
    float e = __expf(-2.f * fabsf(x));
    float t = (1.f - e) / (1.f + e);
    return x >= 0.f ? t : -t;
}

#define WAITV(n) asm volatile("s_waitcnt vmcnt(" #n ")" ::: "memory")
#define MEMFENCE asm volatile("" ::: "memory")

// ---------------------------------------------------------------------------
// ABLATION ROUND: the 5 GRU iterations run 5 mathematically-identical k-loop
// structures; per-dispatch rocprof dur isolates the binding constraint.
//   VAR 0: 4-buf counted-vmcnt pipeline + setprio   (R4 anchor, LDS 80K)
//   VAR 2: VAR0 without setprio                     (LDS 80K, later dispatch)
//   VAR 3: 2-buf plain __syncthreads double-buffer  (LDS 40K)
//   VAR 4: 1-buf fully-serial stage->wait->compute  (LDS 20K)
//   gemm64_k: 64x64 tile, 2-buf, acc=64 regs -> 3 blocks/CU (LDS 32K)
// All share: 128(or 64)x64xNG tile, T2 both-sides B/A swizzle (conflicts==0),
// EPI3 gate sparsity (3 staged B slots), full k-unroll.
// ---------------------------------------------------------------------------
template<int NG, int EPI, int SWZ, int KSTEPS, int KSPLIT, int VAR>
__global__ __launch_bounds__(256, 2) void gemm_k(
    const u16* __restrict__ A, int ldaB,
    const u16* __restrict__ A2, int lda2B,
    const u16* __restrict__ Bw, int ldbB,
    int M,
    u16* __restrict__ C1, int ldc,
    const float* __restrict__ bias,
    const u16* __restrict__ hbuf,
    float* __restrict__ outp, const float* __restrict__ omask)
{
    constexpr int NACC = (EPI == 3) ? 4 : NG;
    constexpr int NBUF = (VAR <= 2) ? 4 : (VAR == 3 ? 2 : 1);
    __shared__ __align__(16) u16 lsA[NBUF][128 * 32];
    __shared__ __align__(16) u16 lsB[NBUF][NG * 64 * 32];

    const int tid = threadIdx.x;
    const int wv = tid >> 6, ln = tid & 63;
    const int wm = wv >> 1, wn = wv & 1;        // 2M x 2N wave grid
    int bxi, byi;
    if constexpr (SWZ) {
        int bid = blockIdx.x;
        int chunk = bid & 7, pos = bid >> 3;
        int orig = chunk * (int)(gridDim.x >> 3) + pos;
        bxi = orig / 5; byi = orig - bxi * 5;
    } else {
        bxi = blockIdx.x; byi = blockIdx.y;
    }
    const int m0 = bxi * 128;
    const int n0 = byi * 64;
    const int lhalf = ln >> 4, l16 = ln & 15;

    f32x4 acc[NACC][4][2];
#pragma unroll
    for (int g = 0; g < NACC; ++g)
#pragma unroll
        for (int r = 0; r < 4; ++r)
#pragma unroll
            for (int c = 0; c < 2; ++c) { f32x4 z = {0.f, 0.f, 0.f, 0.f}; acc[g][r][c] = z; }

    // ---- staging bases (source pre-swizzled; glds dest lane-linear) ----
    const char* pA[2];
    const char* pA2[2];
#pragma unroll
    for (int c = 0; c < 2; ++c) {
        int idx = (wv * 2 + c) * 64 + ln;       // 16B-unit index
        int row = idx >> 2;
        int kb = ((idx & 3) * 16) ^ (((row >> 1) & 3) << 4);
        pA[c]  = (const char*)A  + (size_t)(m0 + row) * ldaB  + kb;
        pA2[c] = (const char*)A2 + (size_t)(m0 + row) * lda2B + kb;
    }
    const int bidx = wv * 64 + ln;
    const int bn = bidx >> 2;
    const int bkb = ((bidx & 3) * 16) ^ (((bn >> 1) & 3) << 4);
    const char* pB[NG];
#pragma unroll
    for (int g = 0; g < NG; ++g)
        pB[g] = (const char*)Bw + (size_t)(g * 320 + n0 + bn) * ldbB + bkb;
    const char* pB2hi = (const char*)Bw + (size_t)(3 * 320 + n0 + bn) * ldbB + bkb;

    auto stage = [&](int ks, int buf) {
#pragma unroll
        for (int c = 0; c < 2; ++c) {
            const char* src = (ks < KSPLIT) ? (pA[c] + ks * 64)
                                            : (pA2[c] + (ks - KSPLIT) * 64);
            async_copy16(src, &lsA[buf][(wv * 2 + c) * 512]);
        }
#pragma unroll
        for (int g = 0; g < NG; ++g) {
            const char* src;
            if constexpr (EPI == 3) {
                if (g == 2) src = ((ks < KSPLIT) ? pB[2] : pB2hi) + ks * 64;
                else        src = pB[g] + ks * 64;
            } else {
                src = pB[g] + ks * 64;
            }
            async_copy16(src, &lsB[buf][g * 2048 + wv * 512]);
        }
    };

    const int rswz = ((l16 >> 1) & 3) << 3;      // read-side swizzle (u16 units)

    auto compute = [&](int j, int buf) {
        if constexpr (VAR == 0) __builtin_amdgcn_s_setprio(1);
        bf16x8 af[4];
#pragma unroll
        for (int r = 0; r < 4; ++r)
            af[r] = *(const bf16x8*)&lsA[buf][(wm * 64 + r * 16 + l16) * 32 + (lhalf * 8 ^ rswz)];
#pragma unroll
        for (int g = 0; g < NG; ++g) {
#pragma unroll
            for (int c = 0; c < 2; ++c) {
                bf16x8 bf = *(const bf16x8*)&lsB[buf][g * 2048 + (wn * 32 + c * 16 + l16) * 32 + (lhalf * 8 ^ rswz)];
#pragma unroll
                for (int r = 0; r < 4; ++r) {
                    if constexpr (EPI == 3) {
                        if (g == 2) {
                            if (j < KSPLIT)
                                acc[2][r][c] = __builtin_amdgcn_mfma_f32_16x16x32_bf16(af[r], bf, acc[2][r][c], 0, 0, 0);
                            else
                                acc[3][r][c] = __builtin_amdgcn_mfma_f32_16x16x32_bf16(af[r], bf, acc[3][r][c], 0, 0, 0);
                        } else {
                            acc[g][r][c] = __builtin_amdgcn_mfma_f32_16x16x32_bf16(af[r], bf, acc[g][r][c], 0, 0, 0);
                        }
                    } else {
                        acc[g][r][c] = __builtin_amdgcn_mfma_f32_16x16x32_bf16(af[r], bf, acc[g][r][c], 0, 0, 0);
                    }
                }
            }
        }
        if constexpr (VAR == 0) __builtin_amdgcn_s_setprio(0);
    };

    if constexpr (VAR <= 2) {
        // 4-buffer counted-vmcnt pipeline (R4-verified)
        stage(0, 0); MEMFENCE; stage(1, 1); MEMFENCE; stage(2, 2);
#pragma unroll
        for (int j = 0; j < KSTEPS; ++j) {
            const int rem = KSTEPS - 1 - j;
            const int d = rem > 2 ? 2 : rem;     // stages legitimately in flight
            if constexpr (NG == 3) {             // LPS = 5
                if (d == 2) WAITV(10); else if (d == 1) WAITV(5); else WAITV(0);
            } else {                             // NG == 1, LPS = 3
                if (d == 2) WAITV(6); else if (d == 1) WAITV(3); else WAITV(0);
            }
            __builtin_amdgcn_s_barrier();
            MEMFENCE;
            if (j + 3 < KSTEPS) stage(j + 3, (j + 3) & 3);
            compute(j, j & 3);
        }
    } else if constexpr (VAR == 3) {
        // 2-buffer plain-syncthreads double-buffer (R3-verified)
        stage(0, 0);
        __syncthreads();
#pragma unroll
        for (int j = 0; j < KSTEPS; ++j) {
            if (j + 1 < KSTEPS) stage(j + 1, (j + 1) & 1);
            compute(j, j & 1);
            __syncthreads();
        }
    } else {
        // 1-buffer fully serial: staging latency fully exposed
#pragma unroll
        for (int j = 0; j < KSTEPS; ++j) {
            stage(j, 0);
            WAITV(0);
            __builtin_amdgcn_s_barrier();
            MEMFENCE;
            compute(j, 0);
            __syncthreads();
        }
    }

    const int mrow_base = m0 + wm * 64;
#pragma unroll
    for (int r = 0; r < 4; ++r) {
#pragma unroll
        for (int c = 0; c < 2; ++c) {
            int nn_ = n0 + wn * 32 + c * 16 + l16;
#pragma unroll
            for (int i = 0; i < 4; ++i) {
                int m = mrow_base + r * 16 + lhalf * 4 + i;
                if (m >= M) continue;
                if constexpr (EPI == 0) {
#pragma unroll
                    for (int g = 0; g < NG; ++g) {
                        float v = acc[g][r][c][i];
                        if (bias != nullptr && nn_ < HIDDEN) v += bias[g * HIDDEN + nn_];
                        C1[(size_t)m * ldc + g * 320 + nn_] = f2bf1(v);
                    }
                } else if constexpr (EPI == 2) {
                    if (nn_ < HIDDEN) {
                        float v = acc[0][r][c][i] + (bias ? bias[nn_] : 0.f);
                        v = fmaxf(v, 0.f);
                        if (omask) v *= omask[m];
                        outp[(size_t)m * HIDDEN + nn_] = v;
                    }
                } else { // EPI == 3: fused GRU
                    float rl = acc[0][r][c][i] + bias[nn_];
                    float zl = acc[1][r][c][i] + bias[320 + nn_];
                    float in_ = acc[2][r][c][i] + bias[640 + nn_];
                    float hn_ = acc[3][r][c][i] + bias[960 + nn_];
                    float hv = bf2f(hbuf[(size_t)m * HP + nn_]);
                    float rr = sigm(rl);
                    float zz = sigm(zl);
                    float nv = tanh_s(in_ + rr * hn_);
                    float msg = (1.f - zz) * nv + zz * hv;
                    if (m == 0) msg = 0.f;
                    C1[(size_t)m * HP + nn_] = f2bf1(msg);
                }
            }
        }
    }
}

// ---------------------------------------------------------------------------
// V1: 64x64 tile, 4 waves as 1M x 4N (wave = 64 rows x 16 cols x gates).
// acc[4][4] f32x4 = 64 regs -> ~164 total -> 3 waves/SIMD (vs 2): occupancy
// test. 2-buf syncthreads structure, LDS 32K (3 blocks/CU, LDS allows 5).
// ---------------------------------------------------------------------------
template<int NG, int KSTEPS, int KSPLIT>
__global__ __launch_bounds__(256, 3) void gemm64_k(
    const u16* __restrict__ A, int ldaB,
    const u16* __restrict__ A2, int lda2B,
    const u16* __restrict__ Bw, int ldbB,
    int M,
    u16* __restrict__ C1, int ldc,
    const float* __restrict__ bias,
    const u16* __restrict__ hbuf)
{
    __shared__ __align__(16) u16 lsA[2][64 * 32];
    __shared__ __align__(16) u16 lsB[2][NG * 64 * 32];

    const int tid = threadIdx.x;
    const int wv = tid >> 6, ln = tid & 63;
    const int wn = wv;                           // 1M x 4N
    int bid = blockIdx.x;
    int chunk = bid & 7, pos = bid >> 3;
    int orig = chunk * (int)(gridDim.x >> 3) + pos;
    int bxi = orig / 5, byi = orig - bxi * 5;
    const int m0 = bxi * 64;
    const int n0 = byi * 64;
    const int lhalf = ln >> 4, l16 = ln & 15;

    f32x4 acc[4][4];
#pragma unroll
    for (int g = 0; g < 4; ++g)
#pragma unroll
        for (int r = 0; r < 4; ++r) { f32x4 z = {0.f, 0.f, 0.f, 0.f}; acc[g][r] = z; }

    // A staging: 64 rows x 64B = 4KB, 1 glds/thread
    int aidx = tid;
    int arow = aidx >> 2;
    int akb = ((aidx & 3) * 16) ^ (((arow >> 1) & 3) << 4);
    const char* pA  = (const char*)A  + (size_t)(m0 + arow) * ldaB  + akb;
    const char* pA2 = (const char*)A2 + (size_t)(m0 + arow) * lda2B + akb;
    // B staging: NG x 4KB
    const int bidx = wv * 64 + ln;
    const int bn = bidx >> 2;
    const int bkb = ((bidx & 3) * 16) ^ (((bn >> 1) & 3) << 4);
    const char* pB[NG];
#pragma unroll
    for (int g = 0; g < NG; ++g)
        pB[g] = (const char*)Bw + (size_t)(g * 320 + n0 + bn) * ldbB + bkb;
    const char* pB2hi = (const char*)Bw + (size_t)(3 * 320 + n0 + bn) * ldbB + bkb;

    auto stage = [&](int ks, int buf) {
        const char* srcA = (ks < KSPLIT) ? (pA + ks * 64) : (pA2 + (ks - KSPLIT) * 64);
        async_copy16(srcA, &lsA[buf][wv * 512]);
#pragma unroll
        for (int g = 0; g < NG; ++g) {
            const char* src;
            if (g == 2) src = ((ks < KSPLIT) ? pB[2] : pB2hi) + ks * 64;
            else        src = pB[g] + ks * 64;
            async_copy16(src, &lsB[buf][g * 2048 + wv * 512]);
        }
    };

    const int rswz = ((l16 >> 1) & 3) << 3;

    auto compute = [&](int j, int buf) {
        bf16x8 af[4];
#pragma unroll
        for (int r = 0; r < 4; ++r)
            af[r] = *(const bf16x8*)&lsA[buf][(r * 16 + l16) * 32 + (lhalf * 8 ^ rswz)];
#pragma unroll
        for (int g = 0; g < NG; ++g) {
            bf16x8 bf = *(const bf16x8*)&lsB[buf][g * 2048 + (wn * 16 + l16) * 32 + (lhalf * 8 ^ rswz)];
            const int gd = (g == 2) ? (j < KSPLIT ? 2 : 3) : g;
#pragma unroll
            for (int r = 0; r < 4; ++r)
                acc[gd][r] = __builtin_amdgcn_mfma_f32_16x16x32_bf16(af[r], bf, acc[gd][r], 0, 0, 0);
        }
    };

    stage(0, 0);
    __syncthreads();
#pragma unroll
    for (int j = 0; j < KSTEPS; ++j) {
        if (j + 1 < KSTEPS) stage(j + 1, (j + 1) & 1);
        compute(j, j & 1);
        __syncthreads();
    }

    const int nn_ = n0 + wn * 16 + l16;
#pragma unroll
    for (int r = 0; r < 4; ++r) {
#pragma unroll
        for (int i = 0; i < 4; ++i) {
            int m = m0 + r * 16 + lhalf * 4 + i;
            if (m >= M) continue;
            float rl = acc[0][r][i] + bias[nn_];
            float zl = acc[1][r][i] + bias[320 + nn_];
            float in_ = acc[2][r][i] + bias[640 + nn_];
            float hn_ = acc[3][r][i] + bias[960 + nn_];
            float hv = bf2f(hbuf[(size_t)m * HP + nn_]);
            float rr = sigm(rl);
            float zz = sigm(zl);
            float nv = tanh_s(in_ + rr * hn_);
            float msg = (1.f - zz) * nv + zz * hv;
            if (m == 0) msg = 0.f;
            C1[(size_t)m * HP + nn_] = f2bf1(msg);
        }
    }
}

// a_message[a, :] = sum_j message[a2b[a,j], :]
__global__ __launch_bounds__(256) void gather_sum_k(
    const u16* __restrict__ msg, const int* __restrict__ a2b, u16* __restrict__ amsg)
{
    int u = blockIdx.x * 256 + threadIdx.x;
    if (u >= N_ATOMS * 40) return;
    int a = u / 40, c = u - a * 40;
    const uint4* mp = (const uint4*)msg;
    float s[8];
#pragma unroll
    for (int t = 0; t < 8; ++t) s[t] = 0.f;
#pragma unroll
    for (int j = 0; j < MAX_NB; ++j) {
        int b = a2b[a * MAX_NB + j];
        uint4 v = mp[(size_t)b * 40 + c];
        s[0] += bf2f((u16)(v.x & 0xffff)); s[1] += bf2f((u16)(v.x >> 16));
        s[2] += bf2f((u16)(v.y & 0xffff)); s[3] += bf2f((u16)(v.y >> 16));
        s[4] += bf2f((u16)(v.z & 0xffff)); s[5] += bf2f((u16)(v.z >> 16));
        s[6] += bf2f((u16)(v.w & 0xffff)); s[7] += bf2f((u16)(v.w >> 16));
    }
    uint4 o;
    o.x = cvt_pk_bf16(s[0], s[1]);
    o.y = cvt_pk_bf16(s[2], s[3]);
    o.z = cvt_pk_bf16(s[4], s[5]);
    o.w = cvt_pk_bf16(s[6], s[7]);
    ((uint4*)amsg)[(size_t)a * 40 + c] = o;
}

// h[b, :] = amsg[b2a[b], :] - msg[b2revb[b], :]
__global__ __launch_bounds__(256) void build_h_k(
    const u16* __restrict__ amsg, const u16* __restrict__ msg,
    const int* __restrict__ b2a, const int* __restrict__ b2revb, u16* __restrict__ h)
{
    int u = blockIdx.x * 256 + threadIdx.x;
    if (u >= N_BONDS * 40) return;
    int b = u / 40, c = u - b * 40;
    uint4 va = ((const uint4*)amsg)[(size_t)b2a[b] * 40 + c];
    uint4 vm = ((const uint4*)msg)[(size_t)b2revb[b] * 40 + c];
    uint4 o;
    o.x = cvt_pk_bf16(bf2f((u16)(va.x & 0xffff)) - bf2f((u16)(vm.x & 0xffff)),
                      bf2f((u16)(va.x >> 16))    - bf2f((u16)(vm.x >> 16)));
    o.y = cvt_pk_bf16(bf2f((u16)(va.y & 0xffff)) - bf2f((u16)(vm.y & 0xffff)),
                      bf2f((u16)(va.y >> 16))    - bf2f((u16)(vm.y >> 16)));
    o.z = cvt_pk_bf16(bf2f((u16)(va.z & 0xffff)) - bf2f((u16)(vm.z & 0xffff)),
                      bf2f((u16)(va.z >> 16))    - bf2f((u16)(vm.z >> 16)));
    o.w = cvt_pk_bf16(bf2f((u16)(va.w & 0xffff)) - bf2f((u16)(vm.w & 0xffff)),
                      bf2f((u16)(va.w >> 16))    - bf2f((u16)(vm.w >> 16)));
    ((uint4*)h)[(size_t)b * 40 + c] = o;
}

// generic pad+cast fp32 -> bf16
__global__ __launch_bounds__(256) void padcast_k(
    const float* __restrict__ src, int srows, int scols,
    u16* __restrict__ dst, int drows, int dcols)
{
    int idx = blockIdx.x * 256 + threadIdx.x;
    if (idx >= drows * dcols) return;
    int r = idx / dcols, c = idx - r * dcols;
    float v = (r < srows && c < scols) ? src[(size_t)r * scols + c] : 0.f;
    dst[idx] = f2bf(v);
}

// Wf[900][160] fp32 = W_ih[900][300] @ W_i[300][147]
__global__ __launch_bounds__(256) void wf_k(
    const float* __restrict__ W_ih, const float* __restrict__ W_i, float* __restrict__ Wf)
{
    int idx = blockIdx.x * 256 + threadIdx.x;
    if (idx >= 900 * 160) return;
    int r = idx / 160, c = idx - r * 160;
    float s = 0.f;
    if (c < BOND_FDIM) {
        for (int k = 0; k < HIDDEN; ++k)
            s += W_ih[(size_t)r * HIDDEN + k] * W_i[(size_t)k * BOND_FDIM + c];
    }
    Wf[idx] = s;
}

// W4[4][320][480]
__global__ __launch_bounds__(256) void prep_W4_k(
    const float* __restrict__ Wf, const float* __restrict__ W_hh, u16* __restrict__ W4)
{
    int idx = blockIdx.x * 256 + threadIdx.x;
    if (idx >= 4 * HP * 480) return;
    int g = idx / (HP * 480); int rem = idx - g * HP * 480;
    int n = rem / 480, k = rem - n * 480;
    float v = 0.f;
    if (n < HIDDEN) {
        if (g <= 1) {
            if (k < KB_PAD) v = Wf[(size_t)(g * HIDDEN + n) * 160 + k];
            else if (k < KB_PAD + HIDDEN) v = W_hh[(size_t)(g * HIDDEN + n) * HIDDEN + (k - KB_PAD)];
        } else if (g == 2) {
            if (k < KB_PAD) v = Wf[(size_t)(2 * HIDDEN + n) * 160 + k];
        } else {
            if (k >= KB_PAD && k < KB_PAD + HIDDEN) v = W_hh[(size_t)(2 * HIDDEN + n) * HIDDEN + (k - KB_PAD)];
        }
    }
    W4[idx] = f2bf(v);
}

// bias4[4*320]
__global__ __launch_bounds__(256) void bias4_k(
    const float* __restrict__ b_ih, const float* __restrict__ b_hh, float* __restrict__ b4)
{
    int idx = blockIdx.x * 256 + threadIdx.x;
    if (idx >= 4 * HP) return;
    int g = idx / HP, n = idx - g * HP;
    float v = 0.f;
    if (n < HIDDEN) {
        if (g == 0) v = b_ih[n] + b_hh[n];
        else if (g == 1) v = b_ih[HIDDEN + n] + b_hh[HIDDEN + n];
        else if (g == 2) v = b_ih[2 * HIDDEN + n];
        else v = b_hh[2 * HIDDEN + n];
    }
    b4[idx] = v;
}

// W_o [300][433] -> [320][480]
__global__ __launch_bounds__(256) void padWo_k(const float* __restrict__ src, u16* __restrict__ dst)
{
    int idx = blockIdx.x * 256 + threadIdx.x;
    if (idx >= HP * 480) return;
    int n = idx / 480, k = idx - n * 480;
    float v = 0.f;
    if (n < HIDDEN) {
        if (k < ATOM_FDIM) v = src[(size_t)n * 433 + k];
        else if (k >= KA_PAD && k < KA_PAD + HIDDEN) v = src[(size_t)n * 433 + ATOM_FDIM + (k - KA_PAD)];
    }
    dst[idx] = f2bf(v);
}

__global__ __launch_bounds__(256) void sentinel_k(float* __restrict__ out, int n)
{
    int i = blockIdx.x * 256 + threadIdx.x;
    if (i < n) out[i] = 31415.0f;
}

extern "C" void kernel_launch(void* const* d_in, const int* in_sizes, int n_in,
                              void* d_out, int out_size, void* d_ws, size_t ws_size,
                              hipStream_t stream)
{
    const float* f_atoms = (const float*)d_in[0];
    const float* f_bonds = (const float*)d_in[1];
    const int*   a2b     = (const int*)d_in[2];
    const int*   b2a     = (const int*)d_in[3];
    const int*   b2revb  = (const int*)d_in[4];
    const float* maskp   = (const float*)d_in[8];
    const float* W_i     = (const float*)d_in[9];
    const float* W_ih    = (const float*)d_in[10];
    const float* W_hh    = (const float*)d_in[11];
    const float* b_ih    = (const float*)d_in[12];
    const float* b_hh    = (const float*)d_in[13];
    const float* W_o_w   = (const float*)d_in[14];
    const float* W_o_b   = (const float*)d_in[15];
    float* out = (float*)d_out;

    char* ws = (char*)d_ws;
    size_t off = 0;
    auto alloc = [&](size_t bytes) -> char* {
        char* p = ws + off;
        off += (bytes + 255) & ~(size_t)255;
        return p;
    };
    u16*   Wi_p   = (u16*)alloc((size_t)HP * KB_PAD * 2);
    u16*   W4     = (u16*)alloc((size_t)4 * HP * 480 * 2);
    u16*   Wo_p   = (u16*)alloc((size_t)HP * 480 * 2);
    float* bias4  = (float*)alloc((size_t)4 * HP * 4);
    float* Wf     = (float*)alloc((size_t)900 * 160 * 4);
    u16*   fa_p   = (u16*)alloc((size_t)NA_PAD * KA_PAD * 2);
    u16*   fb_p   = (u16*)alloc((size_t)NB_PAD * KB_PAD * 2);
    u16*   message= (u16*)alloc((size_t)NB_PAD * HP * 2);
    u16*   hbuf   = (u16*)alloc((size_t)NB_PAD * HP * 2);
    u16*   amsg   = (u16*)alloc((size_t)NA_PAD * HP * 2);

    if (off > ws_size) {
        sentinel_k<<<(out_size + 255) / 256, 256, 0, stream>>>(out, out_size);
        return;
    }

    // --- weight / feature prep ---
    padcast_k<<<(HP * KB_PAD + 255) / 256, 256, 0, stream>>>(W_i, HIDDEN, BOND_FDIM, Wi_p, HP, KB_PAD);
    padcast_k<<<(NB_PAD * KB_PAD + 255) / 256, 256, 0, stream>>>(f_bonds, N_BONDS, BOND_FDIM, fb_p, NB_PAD, KB_PAD);
    padcast_k<<<(NA_PAD * KA_PAD + 255) / 256, 256, 0, stream>>>(f_atoms, N_ATOMS, ATOM_FDIM, fa_p, NA_PAD, KA_PAD);
    wf_k<<<(900 * 160 + 255) / 256, 256, 0, stream>>>(W_ih, W_i, Wf);
    prep_W4_k<<<(4 * HP * 480 + 255) / 256, 256, 0, stream>>>(Wf, W_hh, W4);
    bias4_k<<<(4 * HP + 255) / 256, 256, 0, stream>>>(b_ih, b_hh, bias4);
    padWo_k<<<(HP * 480 + 255) / 256, 256, 0, stream>>>(W_o_w, Wo_p);

    dim3 blk(256);
    dim3 gB(NB_PAD / 128, 5);
    gemm_k<1, 0, 0, 5, 5, 0><<<gB, blk, 0, stream>>>(
        fb_p, KB_PAD * 2, fb_p, KB_PAD * 2, Wi_p, KB_PAD * 2,
        N_BONDS, message, HP, nullptr, nullptr, nullptr, nullptr);

    dim3 gBf(NB_PAD / 128 * 5);      // 3520, %8==0
    dim3 gB64(NB_PAD / 64 * 5);      // 7040, %8==0

    for (int d = 0; d < DEPTH - 1; ++d) {
        gather_sum_k<<<(N_ATOMS * 40 + 255) / 256, 256, 0, stream>>>(message, a2b, amsg);
        build_h_k<<<(N_BONDS * 40 + 255) / 256, 256, 0, stream>>>(amsg, message, b2a, b2revb, hbuf);
        // ABLATION: one structural variant per depth iteration (all identical math)
        if (d == 0) {
            gemm_k<3, 3, 1, 15, 5, 0><<<gBf, blk, 0, stream>>>(
                fb_p, KB_PAD * 2, hbuf, HP * 2, W4, 480 * 2,
                N_BONDS, message, HP, bias4, hbuf, nullptr, nullptr);
        } else if (d == 1) {
            gemm64_k<3, 15, 5><<<gB64, blk, 0, stream>>>(
                fb_p, KB_PAD * 2, hbuf, HP * 2, W4, 480 * 2,
                N_BONDS, message, HP, bias4, hbuf);
        } else if (d == 2) {
            gemm_k<3, 3, 1, 15, 5, 2><<<gBf, blk, 0, stream>>>(
                fb_p, KB_PAD * 2, hbuf, HP * 2, W4, 480 * 2,
                N_BONDS, message, HP, bias4, hbuf, nullptr, nullptr);
        } else if (d == 3) {
            gemm_k<3, 3, 1, 15, 5, 3><<<gBf, blk, 0, stream>>>(
                fb_p, KB_PAD * 2, hbuf, HP * 2, W4, 480 * 2,
                N_BONDS, message, HP, bias4, hbuf, nullptr, nullptr);
        } else {
            gemm_k<3, 3, 1, 15, 5, 4><<<gBf, blk, 0, stream>>>(
                fb_p, KB_PAD * 2, hbuf, HP * 2, W4, 480 * 2,
                N_BONDS, message, HP, bias4, hbuf, nullptr, nullptr);
        }
    }
    gather_sum_k<<<(N_ATOMS * 40 + 255) / 256, 256, 0, stream>>>(message, a2b, amsg);
    dim3 gO(NA_PAD / 128, 5);
    gemm_k<1, 2, 0, 15, 5, 0><<<gO, blk, 0, stream>>>(
        fa_p, KA_PAD * 2, amsg, HP * 2, Wo_p, 480 * 2,
        N_ATOMS, nullptr, 0, W_o_b, nullptr, out, maskp);
}